// Round 1
// 1057.080 us; speedup vs baseline: 1.0001x; 1.0001x over previous
//
#include <hip/hip_runtime.h>
#include <hip/hip_bf16.h>

#define N_NODES 100000
#define N_EDGES 1600000
#define H 128
#define NUM_INV 16
#define BN_EPS 1e-5f

typedef __attribute__((ext_vector_type(8))) short short8;
typedef __attribute__((ext_vector_type(4))) float f32x4;
typedef __attribute__((ext_vector_type(2))) float f32x2;

static __device__ __forceinline__ unsigned short f2b(float x) {
    union { float f; unsigned u; } c; c.f = x;
    unsigned r = c.u + 0x7fffu + ((c.u >> 16) & 1u);
    return (unsigned short)(r >> 16);
}
// packed bf16x2 (one dword) -> f32x2
static __device__ __forceinline__ f32x2 b2f2(unsigned u) {
    union { unsigned u; float f; } lo, hi;
    lo.u = u << 16;
    hi.u = u & 0xffff0000u;
    return (f32x2){lo.f, hi.f};
}
static __device__ __forceinline__ unsigned pack2(f32x2 v) {
    return (unsigned)f2b(v.x) | ((unsigned)f2b(v.y) << 16);
}
static __device__ __forceinline__ f32x2 splat2(float s) { return (f32x2){s, s}; }

// DPP-based wave64 sum: broadcast result to all lanes
template<int CTRL, int RM>
static __device__ __forceinline__ float dppadd(float x) {
    union { float f; int i; } u, s;
    u.f = x;
    s.i = __builtin_amdgcn_update_dpp(0, u.i, CTRL, RM, 0xf, true);
    return x + s.f;
}
static __device__ __forceinline__ float wave_sum_bcast(float p) {
    p = dppadd<0x111, 0xf>(p);   // row_shr:1
    p = dppadd<0x112, 0xf>(p);   // row_shr:2
    p = dppadd<0x114, 0xf>(p);   // row_shr:4
    p = dppadd<0x118, 0xf>(p);   // row_shr:8
    p = dppadd<0x142, 0xa>(p);   // row_bcast:15 -> rows 1,3
    p = dppadd<0x143, 0xc>(p);   // row_bcast:31 -> rows 2,3
    union { float f; int i; } u, r;
    u.f = p;
    r.i = __builtin_amdgcn_readlane(u.i, 63);
    return r.f;
}

// per-edge MAC of edge_attr @ Wc (e must be wave-uniform)
static __device__ __forceinline__ f32x2 ea_mac(const float* __restrict__ ea, int e,
                                               const f32x2* wc2, f32x2 h2) {
    const f32x4* ep = (const f32x4*)(ea + (size_t)e * NUM_INV);
    f32x4 e0 = ep[0], e1 = ep[1], e2 = ep[2], e3 = ep[3];
    float ev[16] = {e0[0],e0[1],e0[2],e0[3], e1[0],e1[1],e1[2],e1[3],
                    e2[0],e2[1],e2[2],e2[3], e3[0],e3[1],e3[2],e3[3]};
    #pragma unroll
    for (int k = 0; k < NUM_INV; ++k) h2 += splat2(ev[k]) * wc2[k];
    return h2;
}

// nontemporal variant: the 102MB ea stream must not thrash Ps out of cache
static __device__ __forceinline__ f32x2 ea_mac_nt(const float* __restrict__ ea, int e,
                                                  const f32x2* wc2, f32x2 h2) {
    const f32x4* ep = (const f32x4*)(ea + (size_t)e * NUM_INV);
    f32x4 e0 = __builtin_nontemporal_load(ep + 0);
    f32x4 e1 = __builtin_nontemporal_load(ep + 1);
    f32x4 e2 = __builtin_nontemporal_load(ep + 2);
    f32x4 e3 = __builtin_nontemporal_load(ep + 3);
    float ev[16] = {e0[0],e0[1],e0[2],e0[3], e1[0],e1[1],e1[2],e1[3],
                    e2[0],e2[1],e2[2],e2[3], e3[0],e3[1],e3[2],e3[3]};
    #pragma unroll
    for (int k = 0; k < NUM_INV; ++k) h2 += splat2(ev[k]) * wc2[k];
    return h2;
}

// ---------------- K0: W1[0:256,:] -> bf16, transposed ----------------------------------
__global__ void k0_wt(const float* __restrict__ W1, unsigned short* __restrict__ Wt) {
    int idx = blockIdx.x * blockDim.x + threadIdx.x;
    if (idx >= 2 * H * H) return;
    int g = idx >> 14;
    int rem = idx & 16383;
    int k = rem >> 7;
    int f = rem & 127;
    Wt[(size_t)g * H * H + (size_t)f * H + k] = f2b(W1[(size_t)(g * H + k) * H + f]);
}

// ---------------- K1: P = X @ W1part (+b1 for send), bf16 MFMA, M-tile 32 ---------------
__global__ __launch_bounds__(256) void k1_gemm(
    const float* __restrict__ x_send, const float* __restrict__ x_rec,
    const unsigned short* __restrict__ Wt, const float* __restrict__ b1,
    unsigned short* __restrict__ P_send, unsigned short* __restrict__ P_rec)
{
    const int g = blockIdx.y;
    const float* X = g ? x_rec : x_send;
    unsigned short* P = g ? P_rec : P_send;
    const int m0 = blockIdx.x * 32;
    const int tid = threadIdx.x;
    const int wave = tid >> 6;
    const int lane = tid & 63;
    const int quad = lane >> 4;
    const int l16 = lane & 15;
    const int n0 = wave * 32;

    const unsigned short* Wg = Wt + (size_t)g * (H * H);

    f32x4 acc[2][2];
    #pragma unroll
    for (int i = 0; i < 2; ++i)
        #pragma unroll
        for (int j = 0; j < 2; ++j)
            acc[i][j] = (f32x4){0.f, 0.f, 0.f, 0.f};

    #pragma unroll
    for (int kt = 0; kt < 4; ++kt) {
        const int kk = kt * 32;
        short8 a[2], b[2];
        #pragma unroll
        for (int ms = 0; ms < 2; ++ms) {
            const float* ap = X + (size_t)(m0 + ms * 16 + l16) * H + kk + quad * 8;
            f32x4 a0 = *(const f32x4*)ap;
            f32x4 a1 = *(const f32x4*)(ap + 4);
            short8 t;
            t[0] = (short)f2b(a0[0]); t[1] = (short)f2b(a0[1]);
            t[2] = (short)f2b(a0[2]); t[3] = (short)f2b(a0[3]);
            t[4] = (short)f2b(a1[0]); t[5] = (short)f2b(a1[1]);
            t[6] = (short)f2b(a1[2]); t[7] = (short)f2b(a1[3]);
            a[ms] = t;
        }
        #pragma unroll
        for (int ns = 0; ns < 2; ++ns)
            b[ns] = *(const short8*)(Wg + (size_t)(n0 + ns * 16 + l16) * H + kk + quad * 8);
        #pragma unroll
        for (int ms = 0; ms < 2; ++ms)
            #pragma unroll
            for (int ns = 0; ns < 2; ++ns)
                acc[ms][ns] = __builtin_amdgcn_mfma_f32_16x16x32_bf16(
                    a[ms], b[ns], acc[ms][ns], 0, 0, 0);
    }

    #pragma unroll
    for (int ms = 0; ms < 2; ++ms) {
        #pragma unroll
        for (int ns = 0; ns < 2; ++ns) {
            int col = n0 + ns * 16 + l16;
            float bias = g ? 0.f : b1[col];
            #pragma unroll
            for (int r = 0; r < 4; ++r) {
                int row = m0 + ms * 16 + quad * 4 + r;
                P[(size_t)row * H + col] = f2b(acc[ms][ns][r] + bias);
            }
        }
    }
}

// ---------------- CSR build ------------------------------------------------------------
__global__ void k_deg(const int* __restrict__ irec, int* __restrict__ deg) {
    int e = blockIdx.x * 256 + threadIdx.x;
    if (e < N_EDGES) atomicAdd(&deg[irec[e]], 1);
}

__global__ __launch_bounds__(512) void k_scanA(const int* __restrict__ deg, int* __restrict__ bsum) {
    __shared__ int sh[512];
    int t = threadIdx.x;
    int n = blockIdx.x * 512 + t;
    int v = (n < N_NODES) ? deg[n] : 0;
    sh[t] = v; __syncthreads();
    for (int d = 1; d < 512; d <<= 1) {
        int x = (t >= d) ? sh[t - d] : 0;
        __syncthreads();
        sh[t] += x;
        __syncthreads();
    }
    if (t == 511) bsum[blockIdx.x] = sh[511];
}

__global__ __launch_bounds__(256) void k_scanB(const int* __restrict__ bsum, int* __restrict__ bbase) {
    __shared__ int sh[256];
    int t = threadIdx.x;
    int v = (t < 196) ? bsum[t] : 0;
    sh[t] = v; __syncthreads();
    for (int d = 1; d < 256; d <<= 1) {
        int x = (t >= d) ? sh[t - d] : 0;
        __syncthreads();
        sh[t] += x;
        __syncthreads();
    }
    if (t < 196) bbase[t] = sh[t] - v;   // exclusive
}

__global__ __launch_bounds__(512) void k_scanC(const int* __restrict__ deg, const int* __restrict__ bbase,
                                               int* __restrict__ off, int* __restrict__ cursor) {
    __shared__ int sh[512];
    int t = threadIdx.x;
    int n = blockIdx.x * 512 + t;
    int v = (n < N_NODES) ? deg[n] : 0;
    sh[t] = v; __syncthreads();
    for (int d = 1; d < 512; d <<= 1) {
        int x = (t >= d) ? sh[t - d] : 0;
        __syncthreads();
        sh[t] += x;
        __syncthreads();
    }
    if (n < N_NODES) {
        int o = bbase[blockIdx.x] + sh[t] - v;   // exclusive prefix
        off[n] = o;
        cursor[n] = o;
    }
}

// old-path permutation (perm + is_csr)
__global__ void k_perm(const int* __restrict__ irec, const int* __restrict__ isend,
                       int* __restrict__ cursor,
                       int* __restrict__ perm, int* __restrict__ is_csr) {
    int e = blockIdx.x * 256 + threadIdx.x;
    if (e >= N_EDGES) return;
    int p = atomicAdd(&cursor[irec[e]], 1);
    perm[p] = e;
    is_csr[p] = isend[e];
}

// new-path: only inverse permutation rp[e] = recv-CSR slot of edge e (sequential write)
__global__ void k_perm_rp(const int* __restrict__ irec, int* __restrict__ cursor,
                          int* __restrict__ rp) {
    int e = blockIdx.x * 256 + threadIdx.x;
    if (e >= N_EDGES) return;
    rp[e] = atomicAdd(&cursor[irec[e]], 1);
}

// ---------------- OLD K2: BN stats, edge-order (fallback path) --------------------------
__global__ __launch_bounds__(256) void k2_stats(
    const unsigned short* __restrict__ Ps, const unsigned short* __restrict__ Pr,
    const int* __restrict__ isend, const int* __restrict__ irec,
    const float* __restrict__ ea, const float* __restrict__ W1,
    float* __restrict__ stats)
{
    const int tid = threadIdx.x;
    const int wave = tid >> 6;
    const int lane = tid & 63;
    const int f0 = lane * 2;
    const float* Wc = W1 + 2 * H * H;

    f32x2 wc2[NUM_INV];
    #pragma unroll
    for (int k = 0; k < NUM_INV; ++k)
        wc2[k] = (f32x2){Wc[k * H + f0], Wc[k * H + f0 + 1]};

    f32x2 s2 = {0.f, 0.f}, q2 = {0.f, 0.f};
    const int nw = gridDim.x * 4;
    int e = blockIdx.x * 4 + wave;
    for (; e + nw < N_EDGES; e += 2 * nw) {
        int e0 = __builtin_amdgcn_readfirstlane(e);
        int e1 = __builtin_amdgcn_readfirstlane(e + nw);
        int is0 = isend[e0], ir0 = irec[e0];
        int is1 = isend[e1], ir1 = irec[e1];
        unsigned ua0 = *(const unsigned*)(Ps + (size_t)is0 * H + f0);
        unsigned ub0 = *(const unsigned*)(Pr + (size_t)ir0 * H + f0);
        unsigned ua1 = *(const unsigned*)(Ps + (size_t)is1 * H + f0);
        unsigned ub1 = *(const unsigned*)(Pr + (size_t)ir1 * H + f0);
        f32x2 h0 = ea_mac(ea, e0, wc2, b2f2(ua0) + b2f2(ub0));
        f32x2 h1 = ea_mac(ea, e1, wc2, b2f2(ua1) + b2f2(ub1));
        s2 += h0 + h1;
        q2 += h0 * h0 + h1 * h1;
    }
    if (e < N_EDGES) {
        int e0 = __builtin_amdgcn_readfirstlane(e);
        int is0 = isend[e0], ir0 = irec[e0];
        unsigned ua0 = *(const unsigned*)(Ps + (size_t)is0 * H + f0);
        unsigned ub0 = *(const unsigned*)(Pr + (size_t)ir0 * H + f0);
        f32x2 h0 = ea_mac(ea, e0, wc2, b2f2(ua0) + b2f2(ub0));
        s2 += h0;
        q2 += h0 * h0;
    }

    __shared__ float rs[4][128];
    __shared__ float rq[4][128];
    rs[wave][f0] = s2.x; rs[wave][f0 + 1] = s2.y;
    rq[wave][f0] = q2.x; rq[wave][f0 + 1] = q2.y;
    __syncthreads();
    if (tid < 128) {
        float ss = rs[0][tid] + rs[1][tid] + rs[2][tid] + rs[3][tid];
        float qq = rq[0][tid] + rq[1][tid] + rq[2][tid] + rq[3][tid];
        float* st = stats + (size_t)(blockIdx.x & 63) * 256;
        atomicAdd(st + tid, ss);
        atomicAdd(st + 128 + tid, qq);
    }
}

// ---------------- NEW kA: edge-order, ONE random gather, writes u into recv-CSR slot ----
__global__ __launch_bounds__(256) void kA_edge(
    const unsigned short* __restrict__ Ps,
    const int* __restrict__ isend, const int* __restrict__ rp,
    const float* __restrict__ ea, const float* __restrict__ W1,
    unsigned short* __restrict__ U, float* __restrict__ statsA)
{
    const int tid = threadIdx.x;
    const int wave = tid >> 6;
    const int lane = tid & 63;
    const int f0 = lane * 2;
    const float* Wc = W1 + 2 * H * H;

    f32x2 wc2[NUM_INV];
    #pragma unroll
    for (int k = 0; k < NUM_INV; ++k)
        wc2[k] = (f32x2){Wc[k * H + f0], Wc[k * H + f0 + 1]};

    f32x2 s2 = {0.f, 0.f}, q2 = {0.f, 0.f};
    const int nw = gridDim.x * 4;
    int e = blockIdx.x * 4 + wave;
    for (; e + nw < N_EDGES; e += 2 * nw) {
        int e0 = __builtin_amdgcn_readfirstlane(e);
        int e1 = __builtin_amdgcn_readfirstlane(e + nw);
        int is0 = isend[e0], is1 = isend[e1];
        int p0 = rp[e0], p1 = rp[e1];
        unsigned ua0 = *(const unsigned*)(Ps + (size_t)is0 * H + f0);
        unsigned ua1 = *(const unsigned*)(Ps + (size_t)is1 * H + f0);
        f32x2 u0 = ea_mac_nt(ea, e0, wc2, b2f2(ua0));
        f32x2 u1 = ea_mac_nt(ea, e1, wc2, b2f2(ua1));
        s2 += u0 + u1;
        q2 += u0 * u0 + u1 * u1;
        __builtin_nontemporal_store(pack2(u0), (unsigned*)(U + (size_t)p0 * H + f0));
        __builtin_nontemporal_store(pack2(u1), (unsigned*)(U + (size_t)p1 * H + f0));
    }
    if (e < N_EDGES) {
        int e0 = __builtin_amdgcn_readfirstlane(e);
        int is0 = isend[e0];
        int p0 = rp[e0];
        unsigned ua0 = *(const unsigned*)(Ps + (size_t)is0 * H + f0);
        f32x2 u0 = ea_mac_nt(ea, e0, wc2, b2f2(ua0));
        s2 += u0;
        q2 += u0 * u0;
        __builtin_nontemporal_store(pack2(u0), (unsigned*)(U + (size_t)p0 * H + f0));
    }

    __shared__ float rs[4][128];
    __shared__ float rq[4][128];
    rs[wave][f0] = s2.x; rs[wave][f0 + 1] = s2.y;
    rq[wave][f0] = q2.x; rq[wave][f0 + 1] = q2.y;
    __syncthreads();
    if (tid < 128) {
        float ss = rs[0][tid] + rs[1][tid] + rs[2][tid] + rs[3][tid];
        float qq = rq[0][tid] + rq[1][tid] + rq[2][tid] + rq[3][tid];
        float* st = statsA + (size_t)(blockIdx.x & 63) * 256;
        atomicAdd(st + tid, ss);
        atomicAdd(st + 128 + tid, qq);
    }
}

// ---------------- NEW kB1: streaming per-node S_n = sum(u rows); close BN variance ------
// sum_e h = sum_e u + sum_n deg*Pr ; sum_e h^2 = sum_e u^2 + 2*sum_n (S_n . Pr_n) + sum_n deg*Pr^2
__global__ __launch_bounds__(256) void kB1_nodes(
    const unsigned short* __restrict__ U, const unsigned short* __restrict__ Pr,
    const int* __restrict__ off, const int* __restrict__ deg,
    float* __restrict__ statsB)
{
    const int tid = threadIdx.x;
    const int wave = tid >> 6;
    const int lane = tid & 63;
    const int f0 = lane * 2;
    const int nwv = gridDim.x * 4;

    f32x2 cr2 = {0.f, 0.f}, pd2 = {0.f, 0.f}, pq2 = {0.f, 0.f};

    for (int n = blockIdx.x * 4 + wave; n < N_NODES; n += nwv) {
        int nu = __builtin_amdgcn_readfirstlane(n);
        int start = off[nu];
        int d = deg[nu];
        f32x2 pr2 = b2f2(*(const unsigned*)(Pr + (size_t)nu * H + f0));
        const unsigned short* up = U + (size_t)start * H;
        f32x2 Sn = {0.f, 0.f};
        int i = 0;
        for (; i + 2 <= d; i += 2) {
            unsigned a = __builtin_nontemporal_load((const unsigned*)(up + (size_t)i * H + f0));
            unsigned b = __builtin_nontemporal_load((const unsigned*)(up + (size_t)(i + 1) * H + f0));
            Sn += b2f2(a) + b2f2(b);
        }
        if (i < d) {
            unsigned a = __builtin_nontemporal_load((const unsigned*)(up + (size_t)i * H + f0));
            Sn += b2f2(a);
        }
        float df = (float)d;
        cr2 += Sn * pr2;
        pd2 += splat2(df) * pr2;
        pq2 += splat2(df) * pr2 * pr2;
    }

    __shared__ float r0[4][128];
    __shared__ float r1[4][128];
    __shared__ float r2[4][128];
    r0[wave][f0] = cr2.x; r0[wave][f0 + 1] = cr2.y;
    r1[wave][f0] = pd2.x; r1[wave][f0 + 1] = pd2.y;
    r2[wave][f0] = pq2.x; r2[wave][f0 + 1] = pq2.y;
    __syncthreads();
    if (tid < 128) {
        float a = r0[0][tid] + r0[1][tid] + r0[2][tid] + r0[3][tid];
        float b = r1[0][tid] + r1[1][tid] + r1[2][tid] + r1[3][tid];
        float c = r2[0][tid] + r2[1][tid] + r2[2][tid] + r2[3][tid];
        float* st = statsB + (size_t)(blockIdx.x & 63) * 384;
        atomicAdd(st + tid, a);
        atomicAdd(st + 128 + tid, b);
        atomicAdd(st + 256 + tid, c);
    }
}

// ---------------- K3 old: finalize BN from direct stats --------------------------------
__global__ void k3_finalize(const float* __restrict__ stats,
                            const float* __restrict__ gamma, const float* __restrict__ beta,
                            float* __restrict__ ssb)
{
    int f = threadIdx.x;
    if (f >= H) return;
    float s = 0.f, q = 0.f;
    for (int b = 0; b < 64; ++b) {
        s += stats[b * 256 + f];
        q += stats[b * 256 + 128 + f];
    }
    const float invE = 1.f / (float)N_EDGES;
    float mean = s * invE;
    float var = q * invE - mean * mean;
    float scale = gamma[f] * rsqrtf(var + BN_EPS);
    ssb[f] = scale;
    ssb[H + f] = beta[f] - mean * scale;
}

// ---------------- K3 new: finalize BN from decomposed stats ----------------------------
__global__ void k3_finalize2(const float* __restrict__ statsA, const float* __restrict__ statsB,
                             const float* __restrict__ gamma, const float* __restrict__ beta,
                             float* __restrict__ ssb)
{
    int f = threadIdx.x;
    if (f >= H) return;
    float s = 0.f, q = 0.f, cr = 0.f, pd = 0.f, pq = 0.f;
    for (int b = 0; b < 64; ++b) {
        s  += statsA[b * 256 + f];
        q  += statsA[b * 256 + 128 + f];
        cr += statsB[b * 384 + f];
        pd += statsB[b * 384 + 128 + f];
        pq += statsB[b * 384 + 256 + f];
    }
    const float invE = 1.f / (float)N_EDGES;
    float mean = (s + pd) * invE;
    float ex2 = (q + 2.f * cr + pq) * invE;
    float var = ex2 - mean * mean;
    float scale = gamma[f] * rsqrtf(var + BN_EPS);
    ssb[f] = scale;
    ssb[H + f] = beta[f] - mean * scale;
}

// ---------------- OLD K4: CSR pass 2 (fallback path) ------------------------------------
__global__ __launch_bounds__(256) void k4_csr(
    const unsigned short* __restrict__ Ps, const unsigned short* __restrict__ Pr,
    const int* __restrict__ perm, const int* __restrict__ is_csr,
    const float* __restrict__ ea, const float* __restrict__ W1,
    const int* __restrict__ off, const int* __restrict__ deg,
    const float* __restrict__ ssb, const float* __restrict__ Winf,
    const float* __restrict__ binf_p, float* __restrict__ out)
{
    const int tid = threadIdx.x;
    const int wave = tid >> 6;
    const int lane = tid & 63;
    const int f0 = lane * 2;
    const float* Wc = W1 + 2 * H * H;

    f32x2 wc2[NUM_INV];
    #pragma unroll
    for (int k = 0; k < NUM_INV; ++k)
        wc2[k] = (f32x2){Wc[k * H + f0], Wc[k * H + f0 + 1]};

    int n = blockIdx.x * 4 + wave;
    int nu = __builtin_amdgcn_readfirstlane(n);
    int start = off[nu];
    int d = deg[nu];

    unsigned ub = *(const unsigned*)(Pr + (size_t)nu * H + f0);
    f32x2 pr2 = b2f2(ub);

    f32x2 sc2 = (f32x2){ssb[f0], ssb[f0 + 1]};
    f32x2 sh2 = (f32x2){ssb[H + f0], ssb[H + f0 + 1]};
    f32x2 wi2 = (f32x2){Winf[f0], Winf[f0 + 1]};
    float bi = binf_p[0];

    f32x2 a2 = {0.f, 0.f};
    int i = 0;
    for (; i + 2 <= d; i += 2) {
        int e0 = __builtin_amdgcn_readfirstlane(perm[start + i]);
        int e1 = __builtin_amdgcn_readfirstlane(perm[start + i + 1]);
        int is0 = __builtin_amdgcn_readfirstlane(is_csr[start + i]);
        int is1 = __builtin_amdgcn_readfirstlane(is_csr[start + i + 1]);
        unsigned ua0 = *(const unsigned*)(Ps + (size_t)is0 * H + f0);
        unsigned ua1 = *(const unsigned*)(Ps + (size_t)is1 * H + f0);
        f32x2 h0 = ea_mac(ea, e0, wc2, pr2 + b2f2(ua0));
        f32x2 h1 = ea_mac(ea, e1, wc2, pr2 + b2f2(ua1));
        h0 = h0 * sc2 + sh2;
        h1 = h1 * sc2 + sh2;
        float A0 = 1.f + __expf(-h0.x), B0 = 1.f + __expf(-h0.y);
        float A1 = 1.f + __expf(-h1.x), B1 = 1.f + __expf(-h1.y);
        float r0 = __builtin_amdgcn_rcpf(A0 * B0);
        float r1 = __builtin_amdgcn_rcpf(A1 * B1);
        f32x2 m0 = (f32x2){h0.x * B0 * r0, h0.y * A0 * r0};
        f32x2 m1 = (f32x2){h1.x * B1 * r1, h1.y * A1 * r1};
        f32x2 pp0 = m0 * wi2;
        f32x2 pp1 = m1 * wi2;
        float pt0 = wave_sum_bcast(pp0.x + pp0.y);
        float pt1 = wave_sum_bcast(pp1.x + pp1.y);
        float ew0 = __builtin_amdgcn_rcpf(1.f + __expf(-(pt0 + bi)));
        float ew1 = __builtin_amdgcn_rcpf(1.f + __expf(-(pt1 + bi)));
        a2 += m0 * splat2(ew0) + m1 * splat2(ew1);
    }
    if (i < d) {
        int e0 = __builtin_amdgcn_readfirstlane(perm[start + i]);
        int is0 = __builtin_amdgcn_readfirstlane(is_csr[start + i]);
        unsigned ua0 = *(const unsigned*)(Ps + (size_t)is0 * H + f0);
        f32x2 h0 = ea_mac(ea, e0, wc2, pr2 + b2f2(ua0));
        h0 = h0 * sc2 + sh2;
        float A0 = 1.f + __expf(-h0.x), B0 = 1.f + __expf(-h0.y);
        float r0 = __builtin_amdgcn_rcpf(A0 * B0);
        f32x2 m0 = (f32x2){h0.x * B0 * r0, h0.y * A0 * r0};
        f32x2 pp0 = m0 * wi2;
        float pt0 = wave_sum_bcast(pp0.x + pp0.y);
        float ew0 = __builtin_amdgcn_rcpf(1.f + __expf(-(pt0 + bi)));
        a2 += m0 * splat2(ew0);
    }
    *(float2*)(out + (size_t)nu * H + f0) = make_float2(a2.x, a2.y);
}

// ---------------- NEW kB2: streaming CSR aggregation (no gathers at all) ----------------
__global__ __launch_bounds__(256) void kB2_csr(
    const unsigned short* __restrict__ U, const unsigned short* __restrict__ Pr,
    const int* __restrict__ off, const int* __restrict__ deg,
    const float* __restrict__ ssb, const float* __restrict__ Winf,
    const float* __restrict__ binf_p, float* __restrict__ out)
{
    const int tid = threadIdx.x;
    const int wave = tid >> 6;
    const int lane = tid & 63;
    const int f0 = lane * 2;

    int n = blockIdx.x * 4 + wave;
    int nu = __builtin_amdgcn_readfirstlane(n);
    int start = off[nu];
    int d = deg[nu];

    f32x2 pr2 = b2f2(*(const unsigned*)(Pr + (size_t)nu * H + f0));
    f32x2 sc2 = (f32x2){ssb[f0], ssb[f0 + 1]};
    f32x2 sh2 = (f32x2){ssb[H + f0], ssb[H + f0 + 1]};
    f32x2 wi2 = (f32x2){Winf[f0], Winf[f0 + 1]};
    float bi = binf_p[0];

    const unsigned short* up = U + (size_t)start * H;

    f32x2 a2 = {0.f, 0.f};
    int i = 0;
    for (; i + 2 <= d; i += 2) {
        unsigned u0 = __builtin_nontemporal_load((const unsigned*)(up + (size_t)i * H + f0));
        unsigned u1 = __builtin_nontemporal_load((const unsigned*)(up + (size_t)(i + 1) * H + f0));
        f32x2 h0 = pr2 + b2f2(u0);
        f32x2 h1 = pr2 + b2f2(u1);
        h0 = h0 * sc2 + sh2;
        h1 = h1 * sc2 + sh2;
        float A0 = 1.f + __expf(-h0.x), B0 = 1.f + __expf(-h0.y);
        float A1 = 1.f + __expf(-h1.x), B1 = 1.f + __expf(-h1.y);
        float r0 = __builtin_amdgcn_rcpf(A0 * B0);
        float r1 = __builtin_amdgcn_rcpf(A1 * B1);
        f32x2 m0 = (f32x2){h0.x * B0 * r0, h0.y * A0 * r0};
        f32x2 m1 = (f32x2){h1.x * B1 * r1, h1.y * A1 * r1};
        f32x2 pp0 = m0 * wi2;
        f32x2 pp1 = m1 * wi2;
        float pt0 = wave_sum_bcast(pp0.x + pp0.y);
        float pt1 = wave_sum_bcast(pp1.x + pp1.y);
        float ew0 = __builtin_amdgcn_rcpf(1.f + __expf(-(pt0 + bi)));
        float ew1 = __builtin_amdgcn_rcpf(1.f + __expf(-(pt1 + bi)));
        a2 += m0 * splat2(ew0) + m1 * splat2(ew1);
    }
    if (i < d) {
        unsigned u0 = __builtin_nontemporal_load((const unsigned*)(up + (size_t)i * H + f0));
        f32x2 h0 = pr2 + b2f2(u0);
        h0 = h0 * sc2 + sh2;
        float A0 = 1.f + __expf(-h0.x), B0 = 1.f + __expf(-h0.y);
        float r0 = __builtin_amdgcn_rcpf(A0 * B0);
        f32x2 m0 = (f32x2){h0.x * B0 * r0, h0.y * A0 * r0};
        f32x2 pp0 = m0 * wi2;
        float pt0 = wave_sum_bcast(pp0.x + pp0.y);
        float ew0 = __builtin_amdgcn_rcpf(1.f + __expf(-(pt0 + bi)));
        a2 += m0 * splat2(ew0);
    }
    *(float2*)(out + (size_t)nu * H + f0) = make_float2(a2.x, a2.y);
}

// ---------------- launcher --------------------------------------------------------------
extern "C" void kernel_launch(void* const* d_in, const int* in_sizes, int n_in,
                              void* d_out, int out_size, void* d_ws, size_t ws_size,
                              hipStream_t stream)
{
    const float* x_send = (const float*)d_in[0];
    const float* x_rec  = (const float*)d_in[1];
    const int*   isend  = (const int*)d_in[2];
    const int*   irec   = (const int*)d_in[3];
    const float* ea     = (const float*)d_in[4];
    const float* W1     = (const float*)d_in[5];
    const float* b1     = (const float*)d_in[6];
    const float* gamma  = (const float*)d_in[7];
    const float* beta   = (const float*)d_in[8];
    const float* Winf   = (const float*)d_in[9];
    const float* binf   = (const float*)d_in[10];
    float* out = (float*)d_out;

    char* ws = (char*)d_ws;

    // ---------------- new path: materialize u in recv-CSR order (needs ~469 MB ws) ------
    const size_t NEW_WS_NEEDED = 468632576ULL;
    if (ws_size >= NEW_WS_NEEDED) {
        unsigned short* Ps = (unsigned short*)(ws);                 // 25,600,000
        unsigned short* Pr = (unsigned short*)(ws + 25600000);      // 25,600,000
        unsigned short* Wt = (unsigned short*)(ws + 51200000);      // 65,536
        float* statsA      = (float*)(ws + 51265536);               // 65,536
        float* statsB      = (float*)(ws + 51331072);               // 98,304
        float* ssb         = (float*)(ws + 51429376);               // 1,024
        int* deg           = (int*)(ws + 51430400);                 // 400,000
        int* off           = (int*)(ws + 51830400);                 // 400,000
        int* cursor        = (int*)(ws + 52230400);                 // 400,000
        int* bsum          = (int*)(ws + 52630400);                 // 1,024
        int* bbase         = (int*)(ws + 52631424);                 // 1,024
        int* rp            = (int*)(ws + 52632448);                 // 6,400,000 -> 59,032,448
        unsigned short* U  = (unsigned short*)(ws + 59032576);      // 409,600,000 (256B aligned)

        hipMemsetAsync(statsA, 0, 64 * 256 * sizeof(float), stream);
        hipMemsetAsync(statsB, 0, 64 * 384 * sizeof(float), stream);
        hipMemsetAsync(deg, 0, N_NODES * sizeof(int), stream);

        k0_wt<<<(2 * H * H + 255) / 256, 256, 0, stream>>>(W1, Wt);
        dim3 g1(3125, 2, 1);
        k1_gemm<<<g1, 256, 0, stream>>>(x_send, x_rec, Wt, b1, Ps, Pr);

        k_deg<<<N_EDGES / 256, 256, 0, stream>>>(irec, deg);
        k_scanA<<<196, 512, 0, stream>>>(deg, bsum);
        k_scanB<<<1, 256, 0, stream>>>(bsum, bbase);
        k_scanC<<<196, 512, 0, stream>>>(deg, bbase, off, cursor);
        k_perm_rp<<<N_EDGES / 256, 256, 0, stream>>>(irec, cursor, rp);

        kA_edge<<<2048, 256, 0, stream>>>(Ps, isend, rp, ea, W1, U, statsA);
        kB1_nodes<<<2048, 256, 0, stream>>>(U, Pr, off, deg, statsB);
        k3_finalize2<<<1, 128, 0, stream>>>(statsA, statsB, gamma, beta, ssb);
        kB2_csr<<<N_NODES / 4, 256, 0, stream>>>(U, Pr, off, deg, ssb, Winf, binf, out);
        return;
    }

    // ---------------- fallback: previous verified path ----------------------------------
    unsigned short* Ps = (unsigned short*)(ws);                     // 25,600,000
    unsigned short* Pr = (unsigned short*)(ws + 25600000);          // 25,600,000
    unsigned short* Wt = (unsigned short*)(ws + 51200000);          // 65,536
    float* stats       = (float*)(ws + 51265536);                   // 65,536
    float* ssb         = (float*)(ws + 51331072);                   // 1,024
    int* deg           = (int*)(ws + 51332096);                     // 400,000
    int* off           = (int*)(ws + 51732096);                     // 400,000
    int* cursor        = (int*)(ws + 52132096);                     // 400,000
    int* bsum          = (int*)(ws + 52532096);                     // 1,024
    int* bbase         = (int*)(ws + 52533120);                     // 1,024
    int* perm          = (int*)(ws + 52534144);                     // 6,400,000
    int* is_csr        = (int*)(ws + 58934144);                     // 6,400,000 -> 65,334,144

    hipMemsetAsync(stats, 0, 64 * 256 * sizeof(float), stream);
    hipMemsetAsync(deg, 0, N_NODES * sizeof(int), stream);

    k0_wt<<<(2 * H * H + 255) / 256, 256, 0, stream>>>(W1, Wt);
    dim3 g1(3125, 2, 1);
    k1_gemm<<<g1, 256, 0, stream>>>(x_send, x_rec, Wt, b1, Ps, Pr);

    k_deg<<<N_EDGES / 256, 256, 0, stream>>>(irec, deg);
    k_scanA<<<196, 512, 0, stream>>>(deg, bsum);
    k_scanB<<<1, 256, 0, stream>>>(bsum, bbase);
    k_scanC<<<196, 512, 0, stream>>>(deg, bbase, off, cursor);
    k_perm<<<N_EDGES / 256, 256, 0, stream>>>(irec, isend, cursor, perm, is_csr);

    k2_stats<<<2048, 256, 0, stream>>>(Ps, Pr, isend, irec, ea, W1, stats);
    k3_finalize<<<1, 128, 0, stream>>>(stats, gamma, beta, ssb);
    k4_csr<<<N_NODES / 4, 256, 0, stream>>>(Ps, Pr, perm, is_csr, ea, W1, off, deg,
                                            ssb, Winf, binf, out);
}

// Round 2
// 846.331 us; speedup vs baseline: 1.2492x; 1.2490x over previous
//
#include <hip/hip_runtime.h>
#include <hip/hip_bf16.h>

#define N_NODES 100000
#define N_EDGES 1600000
#define H 128
#define NUM_INV 16
#define BN_EPS 1e-5f

typedef __attribute__((ext_vector_type(8))) short short8;
typedef __attribute__((ext_vector_type(4))) float f32x4;
typedef __attribute__((ext_vector_type(2))) float f32x2;

static __device__ __forceinline__ unsigned short f2b(float x) {
    union { float f; unsigned u; } c; c.f = x;
    unsigned r = c.u + 0x7fffu + ((c.u >> 16) & 1u);
    return (unsigned short)(r >> 16);
}
// packed bf16x2 (one dword) -> f32x2
static __device__ __forceinline__ f32x2 b2f2(unsigned u) {
    union { unsigned u; float f; } lo, hi;
    lo.u = u << 16;
    hi.u = u & 0xffff0000u;
    return (f32x2){lo.f, hi.f};
}
static __device__ __forceinline__ unsigned pack2(f32x2 v) {
    return (unsigned)f2b(v.x) | ((unsigned)f2b(v.y) << 16);
}
static __device__ __forceinline__ f32x2 splat2(float s) { return (f32x2){s, s}; }

// DPP-based wave64 sum: broadcast result to all lanes
template<int CTRL, int RM>
static __device__ __forceinline__ float dppadd(float x) {
    union { float f; int i; } u, s;
    u.f = x;
    s.i = __builtin_amdgcn_update_dpp(0, u.i, CTRL, RM, 0xf, true);
    return x + s.f;
}
static __device__ __forceinline__ float wave_sum_bcast(float p) {
    p = dppadd<0x111, 0xf>(p);   // row_shr:1
    p = dppadd<0x112, 0xf>(p);   // row_shr:2
    p = dppadd<0x114, 0xf>(p);   // row_shr:4
    p = dppadd<0x118, 0xf>(p);   // row_shr:8
    p = dppadd<0x142, 0xa>(p);   // row_bcast:15 -> rows 1,3
    p = dppadd<0x143, 0xc>(p);   // row_bcast:31 -> rows 2,3
    union { float f; int i; } u, r;
    u.f = p;
    r.i = __builtin_amdgcn_readlane(u.i, 63);
    return r.f;
}

// per-edge MAC of edge_attr (f32) @ Wc ; e/slot must be wave-uniform
static __device__ __forceinline__ f32x2 ea_mac(const float* __restrict__ ea, int e,
                                               const f32x2* wc2, f32x2 h2) {
    const f32x4* ep = (const f32x4*)(ea + (size_t)e * NUM_INV);
    f32x4 e0 = ep[0], e1 = ep[1], e2 = ep[2], e3 = ep[3];
    float ev[16] = {e0[0],e0[1],e0[2],e0[3], e1[0],e1[1],e1[2],e1[3],
                    e2[0],e2[1],e2[2],e2[3], e3[0],e3[1],e3[2],e3[3]};
    #pragma unroll
    for (int k = 0; k < NUM_INV; ++k) h2 += splat2(ev[k]) * wc2[k];
    return h2;
}

// per-edge MAC of CSR-ordered bf16 edge_attr @ Wc ; slot wave-uniform, 32 B stream read
static __device__ __forceinline__ f32x2 ea_mac_b16(const unsigned short* __restrict__ eab,
                                                   int slot, const f32x2* wc2, f32x2 h2) {
    const uint4* p = (const uint4*)(eab + (size_t)slot * NUM_INV);
    uint4 w0 = p[0], w1 = p[1];
    unsigned wv[8] = {w0.x, w0.y, w0.z, w0.w, w1.x, w1.y, w1.z, w1.w};
    #pragma unroll
    for (int k = 0; k < 8; ++k) {
        f32x2 ev = b2f2(wv[k]);
        h2 += splat2(ev.x) * wc2[2 * k] + splat2(ev.y) * wc2[2 * k + 1];
    }
    return h2;
}

// ---------------- K0: W1[0:256,:] -> bf16, transposed ----------------------------------
__global__ void k0_wt(const float* __restrict__ W1, unsigned short* __restrict__ Wt) {
    int idx = blockIdx.x * blockDim.x + threadIdx.x;
    if (idx >= 2 * H * H) return;
    int g = idx >> 14;
    int rem = idx & 16383;
    int k = rem >> 7;
    int f = rem & 127;
    Wt[(size_t)g * H * H + (size_t)f * H + k] = f2b(W1[(size_t)(g * H + k) * H + f]);
}

// ---------------- K1: P = X @ W1part (+b1 for send), bf16 MFMA, M-tile 32 ---------------
__global__ __launch_bounds__(256) void k1_gemm(
    const float* __restrict__ x_send, const float* __restrict__ x_rec,
    const unsigned short* __restrict__ Wt, const float* __restrict__ b1,
    unsigned short* __restrict__ P_send, unsigned short* __restrict__ P_rec)
{
    const int g = blockIdx.y;
    const float* X = g ? x_rec : x_send;
    unsigned short* P = g ? P_rec : P_send;
    const int m0 = blockIdx.x * 32;
    const int tid = threadIdx.x;
    const int wave = tid >> 6;
    const int lane = tid & 63;
    const int quad = lane >> 4;
    const int l16 = lane & 15;
    const int n0 = wave * 32;

    const unsigned short* Wg = Wt + (size_t)g * (H * H);

    f32x4 acc[2][2];
    #pragma unroll
    for (int i = 0; i < 2; ++i)
        #pragma unroll
        for (int j = 0; j < 2; ++j)
            acc[i][j] = (f32x4){0.f, 0.f, 0.f, 0.f};

    #pragma unroll
    for (int kt = 0; kt < 4; ++kt) {
        const int kk = kt * 32;
        short8 a[2], b[2];
        #pragma unroll
        for (int ms = 0; ms < 2; ++ms) {
            const float* ap = X + (size_t)(m0 + ms * 16 + l16) * H + kk + quad * 8;
            f32x4 a0 = *(const f32x4*)ap;
            f32x4 a1 = *(const f32x4*)(ap + 4);
            short8 t;
            t[0] = (short)f2b(a0[0]); t[1] = (short)f2b(a0[1]);
            t[2] = (short)f2b(a0[2]); t[3] = (short)f2b(a0[3]);
            t[4] = (short)f2b(a1[0]); t[5] = (short)f2b(a1[1]);
            t[6] = (short)f2b(a1[2]); t[7] = (short)f2b(a1[3]);
            a[ms] = t;
        }
        #pragma unroll
        for (int ns = 0; ns < 2; ++ns)
            b[ns] = *(const short8*)(Wg + (size_t)(n0 + ns * 16 + l16) * H + kk + quad * 8);
        #pragma unroll
        for (int ms = 0; ms < 2; ++ms)
            #pragma unroll
            for (int ns = 0; ns < 2; ++ns)
                acc[ms][ns] = __builtin_amdgcn_mfma_f32_16x16x32_bf16(
                    a[ms], b[ns], acc[ms][ns], 0, 0, 0);
    }

    #pragma unroll
    for (int ms = 0; ms < 2; ++ms) {
        #pragma unroll
        for (int ns = 0; ns < 2; ++ns) {
            int col = n0 + ns * 16 + l16;
            float bias = g ? 0.f : b1[col];
            #pragma unroll
            for (int r = 0; r < 4; ++r) {
                int row = m0 + ms * 16 + quad * 4 + r;
                P[(size_t)row * H + col] = f2b(acc[ms][ns][r] + bias);
            }
        }
    }
}

// ---------------- CSR build ------------------------------------------------------------
__global__ void k_deg(const int* __restrict__ irec, int* __restrict__ deg) {
    int e = blockIdx.x * 256 + threadIdx.x;
    if (e < N_EDGES) atomicAdd(&deg[irec[e]], 1);
}

__global__ __launch_bounds__(512) void k_scanA(const int* __restrict__ deg, int* __restrict__ bsum) {
    __shared__ int sh[512];
    int t = threadIdx.x;
    int n = blockIdx.x * 512 + t;
    int v = (n < N_NODES) ? deg[n] : 0;
    sh[t] = v; __syncthreads();
    for (int d = 1; d < 512; d <<= 1) {
        int x = (t >= d) ? sh[t - d] : 0;
        __syncthreads();
        sh[t] += x;
        __syncthreads();
    }
    if (t == 511) bsum[blockIdx.x] = sh[511];
}

__global__ __launch_bounds__(256) void k_scanB(const int* __restrict__ bsum, int* __restrict__ bbase) {
    __shared__ int sh[256];
    int t = threadIdx.x;
    int v = (t < 196) ? bsum[t] : 0;
    sh[t] = v; __syncthreads();
    for (int d = 1; d < 256; d <<= 1) {
        int x = (t >= d) ? sh[t - d] : 0;
        __syncthreads();
        sh[t] += x;
        __syncthreads();
    }
    if (t < 196) bbase[t] = sh[t] - v;   // exclusive
}

__global__ __launch_bounds__(512) void k_scanC(const int* __restrict__ deg, const int* __restrict__ bbase,
                                               int* __restrict__ off, int* __restrict__ cursor) {
    __shared__ int sh[512];
    int t = threadIdx.x;
    int n = blockIdx.x * 512 + t;
    int v = (n < N_NODES) ? deg[n] : 0;
    sh[t] = v; __syncthreads();
    for (int d = 1; d < 512; d <<= 1) {
        int x = (t >= d) ? sh[t - d] : 0;
        __syncthreads();
        sh[t] += x;
        __syncthreads();
    }
    if (n < N_NODES) {
        int o = bbase[blockIdx.x] + sh[t] - v;   // exclusive prefix
        off[n] = o;
        cursor[n] = o;
    }
}

__global__ void k_perm(const int* __restrict__ irec, const int* __restrict__ isend,
                       int* __restrict__ cursor,
                       int* __restrict__ perm, int* __restrict__ is_csr) {
    int e = blockIdx.x * 256 + threadIdx.x;
    if (e >= N_EDGES) return;
    int p = atomicAdd(&cursor[irec[e]], 1);
    perm[p] = e;
    is_csr[p] = isend[e];
}

// ---------------- k_permEA: gather ea into CSR order as bf16 ----------------------------
// per-lane random 64 B read (64 distinct lines in flight per wave instr), sequential write
__global__ __launch_bounds__(256) void k_permEA(const int* __restrict__ perm,
                                                const float* __restrict__ ea,
                                                unsigned short* __restrict__ eab)
{
    int p = blockIdx.x * 256 + threadIdx.x;
    if (p >= N_EDGES) return;
    int e = perm[p];
    const f32x4* ep = (const f32x4*)(ea + (size_t)e * NUM_INV);
    f32x4 a = ep[0], b = ep[1], c = ep[2], d = ep[3];
    unsigned o0 = pack2((f32x2){a[0], a[1]});
    unsigned o1 = pack2((f32x2){a[2], a[3]});
    unsigned o2 = pack2((f32x2){b[0], b[1]});
    unsigned o3 = pack2((f32x2){b[2], b[3]});
    unsigned o4 = pack2((f32x2){c[0], c[1]});
    unsigned o5 = pack2((f32x2){c[2], c[3]});
    unsigned o6 = pack2((f32x2){d[0], d[1]});
    unsigned o7 = pack2((f32x2){d[2], d[3]});
    uint4* op = (uint4*)(eab + (size_t)p * NUM_INV);
    op[0] = make_uint4(o0, o1, o2, o3);
    op[1] = make_uint4(o4, o5, o6, o7);
}

// ---------------- k2_csr: BN stats in recv-CSR order -----------------------------------
// MODE 0: ea from CSR-ordered bf16 stream (eab). MODE 2: ea gathered via perm (raw f32).
// Pr is per-node sequential (1 row per node instead of per edge).
template<int MODE>
__global__ __launch_bounds__(256) void k2_csr(
    const unsigned short* __restrict__ Ps, const unsigned short* __restrict__ Pr,
    const int* __restrict__ is_csr, const int* __restrict__ perm,
    const float* __restrict__ ea, const unsigned short* __restrict__ eab,
    const float* __restrict__ W1,
    const int* __restrict__ off, const int* __restrict__ deg,
    float* __restrict__ stats)
{
    const int tid = threadIdx.x;
    const int wave = tid >> 6;
    const int lane = tid & 63;
    const int f0 = lane * 2;
    const float* Wc = W1 + 2 * H * H;

    f32x2 wc2[NUM_INV];
    #pragma unroll
    for (int k = 0; k < NUM_INV; ++k)
        wc2[k] = (f32x2){Wc[k * H + f0], Wc[k * H + f0 + 1]};

    int n = blockIdx.x * 4 + wave;
    int nu = __builtin_amdgcn_readfirstlane(n);
    int start = off[nu];
    int d = deg[nu];

    f32x2 pr2 = b2f2(*(const unsigned*)(Pr + (size_t)nu * H + f0));

    f32x2 s2 = {0.f, 0.f}, q2 = {0.f, 0.f};
    int i = 0;
    for (; i + 2 <= d; i += 2) {
        int is0 = __builtin_amdgcn_readfirstlane(is_csr[start + i]);
        int is1 = __builtin_amdgcn_readfirstlane(is_csr[start + i + 1]);
        unsigned ua0 = *(const unsigned*)(Ps + (size_t)is0 * H + f0);
        unsigned ua1 = *(const unsigned*)(Ps + (size_t)is1 * H + f0);
        f32x2 h0 = pr2 + b2f2(ua0);
        f32x2 h1 = pr2 + b2f2(ua1);
        if (MODE == 0) {
            h0 = ea_mac_b16(eab, start + i, wc2, h0);
            h1 = ea_mac_b16(eab, start + i + 1, wc2, h1);
        } else {
            int e0 = __builtin_amdgcn_readfirstlane(perm[start + i]);
            int e1 = __builtin_amdgcn_readfirstlane(perm[start + i + 1]);
            h0 = ea_mac(ea, e0, wc2, h0);
            h1 = ea_mac(ea, e1, wc2, h1);
        }
        s2 += h0 + h1;
        q2 += h0 * h0 + h1 * h1;
    }
    if (i < d) {
        int is0 = __builtin_amdgcn_readfirstlane(is_csr[start + i]);
        unsigned ua0 = *(const unsigned*)(Ps + (size_t)is0 * H + f0);
        f32x2 h0 = pr2 + b2f2(ua0);
        if (MODE == 0) {
            h0 = ea_mac_b16(eab, start + i, wc2, h0);
        } else {
            int e0 = __builtin_amdgcn_readfirstlane(perm[start + i]);
            h0 = ea_mac(ea, e0, wc2, h0);
        }
        s2 += h0;
        q2 += h0 * h0;
    }

    __shared__ float rs[4][128];
    __shared__ float rq[4][128];
    rs[wave][f0] = s2.x; rs[wave][f0 + 1] = s2.y;
    rq[wave][f0] = q2.x; rq[wave][f0 + 1] = q2.y;
    __syncthreads();
    if (tid < 128) {
        float ss = rs[0][tid] + rs[1][tid] + rs[2][tid] + rs[3][tid];
        float qq = rq[0][tid] + rq[1][tid] + rq[2][tid] + rq[3][tid];
        float* st = stats + (size_t)(blockIdx.x & 63) * 256;
        atomicAdd(st + tid, ss);
        atomicAdd(st + 128 + tid, qq);
    }
}

// ---------------- K3: finalize BN -> per-feature scale/shift ----------------------------
__global__ void k3_finalize(const float* __restrict__ stats,
                            const float* __restrict__ gamma, const float* __restrict__ beta,
                            float* __restrict__ ssb)
{
    int f = threadIdx.x;
    if (f >= H) return;
    float s = 0.f, q = 0.f;
    for (int b = 0; b < 64; ++b) {
        s += stats[b * 256 + f];
        q += stats[b * 256 + 128 + f];
    }
    const float invE = 1.f / (float)N_EDGES;
    float mean = s * invE;
    float var = q * invE - mean * mean;
    float scale = gamma[f] * rsqrtf(var + BN_EPS);
    ssb[f] = scale;
    ssb[H + f] = beta[f] - mean * scale;
}

// ---------------- K4 (fallback): CSR pass 2 with raw ea gather --------------------------
__global__ __launch_bounds__(256) void k4_csr(
    const unsigned short* __restrict__ Ps, const unsigned short* __restrict__ Pr,
    const int* __restrict__ perm, const int* __restrict__ is_csr,
    const float* __restrict__ ea, const float* __restrict__ W1,
    const int* __restrict__ off, const int* __restrict__ deg,
    const float* __restrict__ ssb, const float* __restrict__ Winf,
    const float* __restrict__ binf_p, float* __restrict__ out)
{
    const int tid = threadIdx.x;
    const int wave = tid >> 6;
    const int lane = tid & 63;
    const int f0 = lane * 2;
    const float* Wc = W1 + 2 * H * H;

    f32x2 wc2[NUM_INV];
    #pragma unroll
    for (int k = 0; k < NUM_INV; ++k)
        wc2[k] = (f32x2){Wc[k * H + f0], Wc[k * H + f0 + 1]};

    int n = blockIdx.x * 4 + wave;
    int nu = __builtin_amdgcn_readfirstlane(n);
    int start = off[nu];
    int d = deg[nu];

    unsigned ub = *(const unsigned*)(Pr + (size_t)nu * H + f0);
    f32x2 pr2 = b2f2(ub);

    f32x2 sc2 = (f32x2){ssb[f0], ssb[f0 + 1]};
    f32x2 sh2 = (f32x2){ssb[H + f0], ssb[H + f0 + 1]};
    f32x2 wi2 = (f32x2){Winf[f0], Winf[f0 + 1]};
    float bi = binf_p[0];

    f32x2 a2 = {0.f, 0.f};
    int i = 0;
    for (; i + 2 <= d; i += 2) {
        int e0 = __builtin_amdgcn_readfirstlane(perm[start + i]);
        int e1 = __builtin_amdgcn_readfirstlane(perm[start + i + 1]);
        int is0 = __builtin_amdgcn_readfirstlane(is_csr[start + i]);
        int is1 = __builtin_amdgcn_readfirstlane(is_csr[start + i + 1]);
        unsigned ua0 = *(const unsigned*)(Ps + (size_t)is0 * H + f0);
        unsigned ua1 = *(const unsigned*)(Ps + (size_t)is1 * H + f0);
        f32x2 h0 = ea_mac(ea, e0, wc2, pr2 + b2f2(ua0));
        f32x2 h1 = ea_mac(ea, e1, wc2, pr2 + b2f2(ua1));
        h0 = h0 * sc2 + sh2;
        h1 = h1 * sc2 + sh2;
        float A0 = 1.f + __expf(-h0.x), B0 = 1.f + __expf(-h0.y);
        float A1 = 1.f + __expf(-h1.x), B1 = 1.f + __expf(-h1.y);
        float r0 = __builtin_amdgcn_rcpf(A0 * B0);
        float r1 = __builtin_amdgcn_rcpf(A1 * B1);
        f32x2 m0 = (f32x2){h0.x * B0 * r0, h0.y * A0 * r0};
        f32x2 m1 = (f32x2){h1.x * B1 * r1, h1.y * A1 * r1};
        f32x2 pp0 = m0 * wi2;
        f32x2 pp1 = m1 * wi2;
        float pt0 = wave_sum_bcast(pp0.x + pp0.y);
        float pt1 = wave_sum_bcast(pp1.x + pp1.y);
        float ew0 = __builtin_amdgcn_rcpf(1.f + __expf(-(pt0 + bi)));
        float ew1 = __builtin_amdgcn_rcpf(1.f + __expf(-(pt1 + bi)));
        a2 += m0 * splat2(ew0) + m1 * splat2(ew1);
    }
    if (i < d) {
        int e0 = __builtin_amdgcn_readfirstlane(perm[start + i]);
        int is0 = __builtin_amdgcn_readfirstlane(is_csr[start + i]);
        unsigned ua0 = *(const unsigned*)(Ps + (size_t)is0 * H + f0);
        f32x2 h0 = ea_mac(ea, e0, wc2, pr2 + b2f2(ua0));
        h0 = h0 * sc2 + sh2;
        float A0 = 1.f + __expf(-h0.x), B0 = 1.f + __expf(-h0.y);
        float r0 = __builtin_amdgcn_rcpf(A0 * B0);
        f32x2 m0 = (f32x2){h0.x * B0 * r0, h0.y * A0 * r0};
        f32x2 pp0 = m0 * wi2;
        float pt0 = wave_sum_bcast(pp0.x + pp0.y);
        float ew0 = __builtin_amdgcn_rcpf(1.f + __expf(-(pt0 + bi)));
        a2 += m0 * splat2(ew0);
    }
    *(float2*)(out + (size_t)nu * H + f0) = make_float2(a2.x, a2.y);
}

// ---------------- K4B: CSR pass 2 with streaming bf16 ea_csr ----------------------------
__global__ __launch_bounds__(256) void k4_csrB(
    const unsigned short* __restrict__ Ps, const unsigned short* __restrict__ Pr,
    const int* __restrict__ is_csr, const unsigned short* __restrict__ eab,
    const float* __restrict__ W1,
    const int* __restrict__ off, const int* __restrict__ deg,
    const float* __restrict__ ssb, const float* __restrict__ Winf,
    const float* __restrict__ binf_p, float* __restrict__ out)
{
    const int tid = threadIdx.x;
    const int wave = tid >> 6;
    const int lane = tid & 63;
    const int f0 = lane * 2;
    const float* Wc = W1 + 2 * H * H;

    f32x2 wc2[NUM_INV];
    #pragma unroll
    for (int k = 0; k < NUM_INV; ++k)
        wc2[k] = (f32x2){Wc[k * H + f0], Wc[k * H + f0 + 1]};

    int n = blockIdx.x * 4 + wave;
    int nu = __builtin_amdgcn_readfirstlane(n);
    int start = off[nu];
    int d = deg[nu];

    f32x2 pr2 = b2f2(*(const unsigned*)(Pr + (size_t)nu * H + f0));
    f32x2 sc2 = (f32x2){ssb[f0], ssb[f0 + 1]};
    f32x2 sh2 = (f32x2){ssb[H + f0], ssb[H + f0 + 1]};
    f32x2 wi2 = (f32x2){Winf[f0], Winf[f0 + 1]};
    float bi = binf_p[0];

    f32x2 a2 = {0.f, 0.f};
    int i = 0;
    for (; i + 2 <= d; i += 2) {
        int is0 = __builtin_amdgcn_readfirstlane(is_csr[start + i]);
        int is1 = __builtin_amdgcn_readfirstlane(is_csr[start + i + 1]);
        unsigned ua0 = *(const unsigned*)(Ps + (size_t)is0 * H + f0);
        unsigned ua1 = *(const unsigned*)(Ps + (size_t)is1 * H + f0);
        f32x2 h0 = ea_mac_b16(eab, start + i, wc2, pr2 + b2f2(ua0));
        f32x2 h1 = ea_mac_b16(eab, start + i + 1, wc2, pr2 + b2f2(ua1));
        h0 = h0 * sc2 + sh2;
        h1 = h1 * sc2 + sh2;
        float A0 = 1.f + __expf(-h0.x), B0 = 1.f + __expf(-h0.y);
        float A1 = 1.f + __expf(-h1.x), B1 = 1.f + __expf(-h1.y);
        float r0 = __builtin_amdgcn_rcpf(A0 * B0);
        float r1 = __builtin_amdgcn_rcpf(A1 * B1);
        f32x2 m0 = (f32x2){h0.x * B0 * r0, h0.y * A0 * r0};
        f32x2 m1 = (f32x2){h1.x * B1 * r1, h1.y * A1 * r1};
        f32x2 pp0 = m0 * wi2;
        f32x2 pp1 = m1 * wi2;
        float pt0 = wave_sum_bcast(pp0.x + pp0.y);
        float pt1 = wave_sum_bcast(pp1.x + pp1.y);
        float ew0 = __builtin_amdgcn_rcpf(1.f + __expf(-(pt0 + bi)));
        float ew1 = __builtin_amdgcn_rcpf(1.f + __expf(-(pt1 + bi)));
        a2 += m0 * splat2(ew0) + m1 * splat2(ew1);
    }
    if (i < d) {
        int is0 = __builtin_amdgcn_readfirstlane(is_csr[start + i]);
        unsigned ua0 = *(const unsigned*)(Ps + (size_t)is0 * H + f0);
        f32x2 h0 = ea_mac_b16(eab, start + i, wc2, pr2 + b2f2(ua0));
        h0 = h0 * sc2 + sh2;
        float A0 = 1.f + __expf(-h0.x), B0 = 1.f + __expf(-h0.y);
        float r0 = __builtin_amdgcn_rcpf(A0 * B0);
        f32x2 m0 = (f32x2){h0.x * B0 * r0, h0.y * A0 * r0};
        f32x2 pp0 = m0 * wi2;
        float pt0 = wave_sum_bcast(pp0.x + pp0.y);
        float ew0 = __builtin_amdgcn_rcpf(1.f + __expf(-(pt0 + bi)));
        a2 += m0 * splat2(ew0);
    }
    *(float2*)(out + (size_t)nu * H + f0) = make_float2(a2.x, a2.y);
}

// ---------------- launcher --------------------------------------------------------------
extern "C" void kernel_launch(void* const* d_in, const int* in_sizes, int n_in,
                              void* d_out, int out_size, void* d_ws, size_t ws_size,
                              hipStream_t stream)
{
    const float* x_send = (const float*)d_in[0];
    const float* x_rec  = (const float*)d_in[1];
    const int*   isend  = (const int*)d_in[2];
    const int*   irec   = (const int*)d_in[3];
    const float* ea     = (const float*)d_in[4];
    const float* W1     = (const float*)d_in[5];
    const float* b1     = (const float*)d_in[6];
    const float* gamma  = (const float*)d_in[7];
    const float* beta   = (const float*)d_in[8];
    const float* Winf   = (const float*)d_in[9];
    const float* binf   = (const float*)d_in[10];
    float* out = (float*)d_out;

    char* ws = (char*)d_ws;
    // shared base layout (identical to verified fallback)
    unsigned short* Ps = (unsigned short*)(ws);                     // 25,600,000
    unsigned short* Pr = (unsigned short*)(ws + 25600000);          // 25,600,000
    unsigned short* Wt = (unsigned short*)(ws + 51200000);          // 65,536
    float* stats       = (float*)(ws + 51265536);                   // 65,536
    float* ssb         = (float*)(ws + 51331072);                   // 1,024
    int* deg           = (int*)(ws + 51332096);                     // 400,000
    int* off           = (int*)(ws + 51732096);                     // 400,000
    int* cursor        = (int*)(ws + 52132096);                     // 400,000
    int* bsum          = (int*)(ws + 52532096);                     // 1,024
    int* bbase         = (int*)(ws + 52533120);                     // 1,024
    int* perm          = (int*)(ws + 52534144);                     // 6,400,000
    int* is_csr        = (int*)(ws + 58934144);                     // 6,400,000 -> 65,334,144
    unsigned short* eab = (unsigned short*)(ws + 65334272);         // 51,200,000 -> 116,534,272

    const size_t WS_EAB_NEED = 116534272ULL;
    const int use_eab = (ws_size >= WS_EAB_NEED) ? 1 : 0;

    hipMemsetAsync(stats, 0, 64 * 256 * sizeof(float), stream);
    hipMemsetAsync(deg, 0, N_NODES * sizeof(int), stream);

    k0_wt<<<(2 * H * H + 255) / 256, 256, 0, stream>>>(W1, Wt);
    dim3 g1(3125, 2, 1);
    k1_gemm<<<g1, 256, 0, stream>>>(x_send, x_rec, Wt, b1, Ps, Pr);

    k_deg<<<N_EDGES / 256, 256, 0, stream>>>(irec, deg);
    k_scanA<<<196, 512, 0, stream>>>(deg, bsum);
    k_scanB<<<1, 256, 0, stream>>>(bsum, bbase);
    k_scanC<<<196, 512, 0, stream>>>(deg, bbase, off, cursor);
    k_perm<<<N_EDGES / 256, 256, 0, stream>>>(irec, isend, cursor, perm, is_csr);

    if (use_eab) {
        // pay ea's random line once (per-lane gather = max MLP), then stream it twice
        k_permEA<<<N_EDGES / 256, 256, 0, stream>>>(perm, ea, eab);
        k2_csr<0><<<N_NODES / 4, 256, 0, stream>>>(Ps, Pr, is_csr, perm, ea, eab, W1,
                                                   off, deg, stats);
        k3_finalize<<<1, 128, 0, stream>>>(stats, gamma, beta, ssb);
        k4_csrB<<<N_NODES / 4, 256, 0, stream>>>(Ps, Pr, is_csr, eab, W1, off, deg,
                                                 ssb, Winf, binf, out);
    } else {
        // no extra workspace: stats still moves to CSR order (Pr per-node instead of per-edge)
        k2_csr<2><<<N_NODES / 4, 256, 0, stream>>>(Ps, Pr, is_csr, perm, ea, (const unsigned short*)0,
                                                   W1, off, deg, stats);
        k3_finalize<<<1, 128, 0, stream>>>(stats, gamma, beta, ssb);
        k4_csr<<<N_NODES / 4, 256, 0, stream>>>(Ps, Pr, perm, is_csr, ea, W1, off, deg,
                                                ssb, Winf, binf, out);
    }
}

// Round 4
// 790.291 us; speedup vs baseline: 1.3378x; 1.0709x over previous
//
#include <hip/hip_runtime.h>
#include <hip/hip_bf16.h>

#define N_NODES 100000
#define N_EDGES 1600000
#define H 128
#define NUM_INV 16
#define BN_EPS 1e-5f

typedef __attribute__((ext_vector_type(8))) short short8;
typedef __attribute__((ext_vector_type(4))) float f32x4;
typedef __attribute__((ext_vector_type(2))) float f32x2;
typedef __attribute__((ext_vector_type(4))) unsigned u32x4;
typedef _Float16 __attribute__((ext_vector_type(2))) f16x2;

static __device__ __forceinline__ unsigned short f2b(float x) {
    union { float f; unsigned u; } c; c.f = x;
    unsigned r = c.u + 0x7fffu + ((c.u >> 16) & 1u);
    return (unsigned short)(r >> 16);
}
// packed bf16x2 (one dword) -> f32x2
static __device__ __forceinline__ f32x2 b2f2(unsigned u) {
    union { unsigned u; float f; } lo, hi;
    lo.u = u << 16;
    hi.u = u & 0xffff0000u;
    return (f32x2){lo.f, hi.f};
}
static __device__ __forceinline__ f32x2 splat2(float s) { return (f32x2){s, s}; }

// pack two floats into one dword of two f16 (RTNE)
static __device__ __forceinline__ unsigned packf16(float a, float b) {
    union { f16x2 h; unsigned u; } c;
    c.h = (f16x2){(_Float16)a, (_Float16)b};
    return c.u;
}

// DPP-based wave64 sum: broadcast result to all lanes
template<int CTRL, int RM>
static __device__ __forceinline__ float dppadd(float x) {
    union { float f; int i; } u, s;
    u.f = x;
    s.i = __builtin_amdgcn_update_dpp(0, u.i, CTRL, RM, 0xf, true);
    return x + s.f;
}
static __device__ __forceinline__ float wave_sum_bcast(float p) {
    p = dppadd<0x111, 0xf>(p);   // row_shr:1
    p = dppadd<0x112, 0xf>(p);   // row_shr:2
    p = dppadd<0x114, 0xf>(p);   // row_shr:4
    p = dppadd<0x118, 0xf>(p);   // row_shr:8
    p = dppadd<0x142, 0xa>(p);   // row_bcast:15 -> rows 1,3
    p = dppadd<0x143, 0xc>(p);   // row_bcast:31 -> rows 2,3
    union { float f; int i; } u, r;
    u.f = p;
    r.i = __builtin_amdgcn_readlane(u.i, 63);
    return r.f;
}

// per-edge MAC of edge_attr (f32) @ Wc ; e must be wave-uniform (fallback path)
static __device__ __forceinline__ f32x2 ea_mac(const float* __restrict__ ea, int e,
                                               const f32x2* wc2, f32x2 h2) {
    const f32x4* ep = (const f32x4*)(ea + (size_t)e * NUM_INV);
    f32x4 e0 = ep[0], e1 = ep[1], e2 = ep[2], e3 = ep[3];
    float ev[16] = {e0[0],e0[1],e0[2],e0[3], e1[0],e1[1],e1[2],e1[3],
                    e2[0],e2[1],e2[2],e2[3], e3[0],e3[1],e3[2],e3[3]};
    #pragma unroll
    for (int k = 0; k < NUM_INV; ++k) h2 += splat2(ev[k]) * wc2[k];
    return h2;
}

// per-edge MAC of CSR-ordered f16 edge_attr @ Wc(f16 pairs), via v_pk_fma_f16 + op_sel
// broadcast. slot wave-uniform; 16 VOP3P instructions, no unpacks.
static __device__ __forceinline__ f32x2 ea_mac_f16(const unsigned short* __restrict__ eaf,
                                                   int slot, const unsigned* wc16, f32x2 h2) {
    const u32x4* p = (const u32x4*)(eaf + (size_t)slot * NUM_INV);
    u32x4 w0 = __builtin_nontemporal_load(p);
    u32x4 w1 = __builtin_nontemporal_load(p + 1);
    unsigned wv[8] = {w0.x, w0.y, w0.z, w0.w, w1.x, w1.y, w1.z, w1.w};
    f16x2 acc = (f16x2){(_Float16)0.f, (_Float16)0.f};
    #pragma unroll
    for (int k = 0; k < 8; ++k) {
        // lo half of wv[k] (= ea[2k]) broadcast to both lanes, times wc pair of inv 2k
        asm("v_pk_fma_f16 %0, %1, %2, %0 op_sel:[0,0,0] op_sel_hi:[0,1,1]"
            : "+v"(acc) : "v"(wv[k]), "v"(wc16[2 * k]));
        // hi half of wv[k] (= ea[2k+1]) broadcast, times wc pair of inv 2k+1
        asm("v_pk_fma_f16 %0, %1, %2, %0 op_sel:[1,0,0] op_sel_hi:[1,1,1]"
            : "+v"(acc) : "v"(wv[k]), "v"(wc16[2 * k + 1]));
    }
    h2.x += (float)acc.x;
    h2.y += (float)acc.y;
    return h2;
}

// ---------------- K0: W1[0:256,:] -> bf16, transposed ----------------------------------
__global__ void k0_wt(const float* __restrict__ W1, unsigned short* __restrict__ Wt) {
    int idx = blockIdx.x * blockDim.x + threadIdx.x;
    if (idx >= 2 * H * H) return;
    int g = idx >> 14;
    int rem = idx & 16383;
    int k = rem >> 7;
    int f = rem & 127;
    Wt[(size_t)g * H * H + (size_t)f * H + k] = f2b(W1[(size_t)(g * H + k) * H + f]);
}

// ---------------- K1: P = X @ W1part (+b1 for send), bf16 MFMA, M-tile 32 ---------------
__global__ __launch_bounds__(256) void k1_gemm(
    const float* __restrict__ x_send, const float* __restrict__ x_rec,
    const unsigned short* __restrict__ Wt, const float* __restrict__ b1,
    unsigned short* __restrict__ P_send, unsigned short* __restrict__ P_rec)
{
    const int g = blockIdx.y;
    const float* X = g ? x_rec : x_send;
    unsigned short* P = g ? P_rec : P_send;
    const int m0 = blockIdx.x * 32;
    const int tid = threadIdx.x;
    const int wave = tid >> 6;
    const int lane = tid & 63;
    const int quad = lane >> 4;
    const int l16 = lane & 15;
    const int n0 = wave * 32;

    const unsigned short* Wg = Wt + (size_t)g * (H * H);

    f32x4 acc[2][2];
    #pragma unroll
    for (int i = 0; i < 2; ++i)
        #pragma unroll
        for (int j = 0; j < 2; ++j)
            acc[i][j] = (f32x4){0.f, 0.f, 0.f, 0.f};

    #pragma unroll
    for (int kt = 0; kt < 4; ++kt) {
        const int kk = kt * 32;
        short8 a[2], b[2];
        #pragma unroll
        for (int ms = 0; ms < 2; ++ms) {
            const float* ap = X + (size_t)(m0 + ms * 16 + l16) * H + kk + quad * 8;
            f32x4 a0 = *(const f32x4*)ap;
            f32x4 a1 = *(const f32x4*)(ap + 4);
            short8 t;
            t[0] = (short)f2b(a0[0]); t[1] = (short)f2b(a0[1]);
            t[2] = (short)f2b(a0[2]); t[3] = (short)f2b(a0[3]);
            t[4] = (short)f2b(a1[0]); t[5] = (short)f2b(a1[1]);
            t[6] = (short)f2b(a1[2]); t[7] = (short)f2b(a1[3]);
            a[ms] = t;
        }
        #pragma unroll
        for (int ns = 0; ns < 2; ++ns)
            b[ns] = *(const short8*)(Wg + (size_t)(n0 + ns * 16 + l16) * H + kk + quad * 8);
        #pragma unroll
        for (int ms = 0; ms < 2; ++ms)
            #pragma unroll
            for (int ns = 0; ns < 2; ++ns)
                acc[ms][ns] = __builtin_amdgcn_mfma_f32_16x16x32_bf16(
                    a[ms], b[ns], acc[ms][ns], 0, 0, 0);
    }

    #pragma unroll
    for (int ms = 0; ms < 2; ++ms) {
        #pragma unroll
        for (int ns = 0; ns < 2; ++ns) {
            int col = n0 + ns * 16 + l16;
            float bias = g ? 0.f : b1[col];
            #pragma unroll
            for (int r = 0; r < 4; ++r) {
                int row = m0 + ms * 16 + quad * 4 + r;
                P[(size_t)row * H + col] = f2b(acc[ms][ns][r] + bias);
            }
        }
    }
}

// ---------------- CSR build ------------------------------------------------------------
__global__ void k_deg(const int* __restrict__ irec, int* __restrict__ deg) {
    int e = blockIdx.x * 256 + threadIdx.x;
    if (e < N_EDGES) atomicAdd(&deg[irec[e]], 1);
}

__global__ __launch_bounds__(512) void k_scanA(const int* __restrict__ deg, int* __restrict__ bsum) {
    __shared__ int sh[512];
    int t = threadIdx.x;
    int n = blockIdx.x * 512 + t;
    int v = (n < N_NODES) ? deg[n] : 0;
    sh[t] = v; __syncthreads();
    for (int d = 1; d < 512; d <<= 1) {
        int x = (t >= d) ? sh[t - d] : 0;
        __syncthreads();
        sh[t] += x;
        __syncthreads();
    }
    if (t == 511) bsum[blockIdx.x] = sh[511];
}

__global__ __launch_bounds__(256) void k_scanB(const int* __restrict__ bsum, int* __restrict__ bbase) {
    __shared__ int sh[256];
    int t = threadIdx.x;
    int v = (t < 196) ? bsum[t] : 0;
    sh[t] = v; __syncthreads();
    for (int d = 1; d < 256; d <<= 1) {
        int x = (t >= d) ? sh[t - d] : 0;
        __syncthreads();
        sh[t] += x;
        __syncthreads();
    }
    if (t < 196) bbase[t] = sh[t] - v;   // exclusive
}

__global__ __launch_bounds__(512) void k_scanC(const int* __restrict__ deg, const int* __restrict__ bbase,
                                               int* __restrict__ off, int* __restrict__ cursor) {
    __shared__ int sh[512];
    int t = threadIdx.x;
    int n = blockIdx.x * 512 + t;
    int v = (n < N_NODES) ? deg[n] : 0;
    sh[t] = v; __syncthreads();
    for (int d = 1; d < 512; d <<= 1) {
        int x = (t >= d) ? sh[t - d] : 0;
        __syncthreads();
        sh[t] += x;
        __syncthreads();
    }
    if (n < N_NODES) {
        int o = bbase[blockIdx.x] + sh[t] - v;   // exclusive prefix
        off[n] = o;
        cursor[n] = o;
    }
}

// fallback-path permutation (perm + is_csr)
__global__ void k_perm(const int* __restrict__ irec, const int* __restrict__ isend,
                       int* __restrict__ cursor,
                       int* __restrict__ perm, int* __restrict__ is_csr) {
    int e = blockIdx.x * 256 + threadIdx.x;
    if (e >= N_EDGES) return;
    int p = atomicAdd(&cursor[irec[e]], 1);
    perm[p] = e;
    is_csr[p] = isend[e];
}

// fused permutation: write is_csr AND f16 edge-attrs directly into CSR slot.
// ea read is fully sequential; no perm[] array, no separate gather pass.
__global__ __launch_bounds__(256) void k_permB(
    const int* __restrict__ irec, const int* __restrict__ isend,
    int* __restrict__ cursor, const float* __restrict__ ea,
    int* __restrict__ is_csr, unsigned short* __restrict__ eaf)
{
    int e = blockIdx.x * 256 + threadIdx.x;
    if (e >= N_EDGES) return;
    int p = atomicAdd(&cursor[irec[e]], 1);
    is_csr[p] = isend[e];
    const f32x4* ep = (const f32x4*)(ea + (size_t)e * NUM_INV);
    f32x4 a = ep[0], b = ep[1], c = ep[2], d = ep[3];
    u32x4 o0, o1;
    o0.x = packf16(a[0], a[1]);
    o0.y = packf16(a[2], a[3]);
    o0.z = packf16(b[0], b[1]);
    o0.w = packf16(b[2], b[3]);
    o1.x = packf16(c[0], c[1]);
    o1.y = packf16(c[2], c[3]);
    o1.z = packf16(d[0], d[1]);
    o1.w = packf16(d[2], d[3]);
    u32x4* op = (u32x4*)(eaf + (size_t)p * NUM_INV);
    op[0] = o0;
    op[1] = o1;
}

// ---------------- k2_csr: BN stats in recv-CSR order -----------------------------------
// MODE 0: ea from CSR-ordered f16 stream (eaf), pk_fma. MODE 2: ea gathered via perm (f32).
template<int MODE>
__global__ __launch_bounds__(256) void k2_csr(
    const unsigned short* __restrict__ Ps, const unsigned short* __restrict__ Pr,
    const int* __restrict__ is_csr, const int* __restrict__ perm,
    const float* __restrict__ ea, const unsigned short* __restrict__ eaf,
    const float* __restrict__ W1,
    const int* __restrict__ off, const int* __restrict__ deg,
    float* __restrict__ stats)
{
    const int tid = threadIdx.x;
    const int wave = tid >> 6;
    const int lane = tid & 63;
    const int f0 = lane * 2;
    const float* Wc = W1 + 2 * H * H;

    f32x2 wc2[(MODE == 2) ? NUM_INV : 1];
    unsigned wc16[(MODE == 0) ? NUM_INV : 1];
    if (MODE == 2) {
        #pragma unroll
        for (int k = 0; k < NUM_INV; ++k)
            wc2[k] = (f32x2){Wc[k * H + f0], Wc[k * H + f0 + 1]};
    } else {
        #pragma unroll
        for (int k = 0; k < NUM_INV; ++k)
            wc16[k] = packf16(Wc[k * H + f0], Wc[k * H + f0 + 1]);
    }

    int n = blockIdx.x * 4 + wave;
    int nu = __builtin_amdgcn_readfirstlane(n);
    int start = off[nu];
    int d = deg[nu];

    f32x2 pr2 = b2f2(*(const unsigned*)(Pr + (size_t)nu * H + f0));

    f32x2 s2 = {0.f, 0.f}, q2 = {0.f, 0.f};
    int i = 0;
    for (; i + 2 <= d; i += 2) {
        int is0 = __builtin_amdgcn_readfirstlane(is_csr[start + i]);
        int is1 = __builtin_amdgcn_readfirstlane(is_csr[start + i + 1]);
        unsigned ua0 = *(const unsigned*)(Ps + (size_t)is0 * H + f0);
        unsigned ua1 = *(const unsigned*)(Ps + (size_t)is1 * H + f0);
        f32x2 h0 = pr2 + b2f2(ua0);
        f32x2 h1 = pr2 + b2f2(ua1);
        if (MODE == 0) {
            h0 = ea_mac_f16(eaf, start + i, wc16, h0);
            h1 = ea_mac_f16(eaf, start + i + 1, wc16, h1);
        } else {
            int e0 = __builtin_amdgcn_readfirstlane(perm[start + i]);
            int e1 = __builtin_amdgcn_readfirstlane(perm[start + i + 1]);
            h0 = ea_mac(ea, e0, wc2, h0);
            h1 = ea_mac(ea, e1, wc2, h1);
        }
        s2 += h0 + h1;
        q2 += h0 * h0 + h1 * h1;
    }
    if (i < d) {
        int is0 = __builtin_amdgcn_readfirstlane(is_csr[start + i]);
        unsigned ua0 = *(const unsigned*)(Ps + (size_t)is0 * H + f0);
        f32x2 h0 = pr2 + b2f2(ua0);
        if (MODE == 0) {
            h0 = ea_mac_f16(eaf, start + i, wc16, h0);
        } else {
            int e0 = __builtin_amdgcn_readfirstlane(perm[start + i]);
            h0 = ea_mac(ea, e0, wc2, h0);
        }
        s2 += h0;
        q2 += h0 * h0;
    }

    __shared__ float rs[4][128];
    __shared__ float rq[4][128];
    rs[wave][f0] = s2.x; rs[wave][f0 + 1] = s2.y;
    rq[wave][f0] = q2.x; rq[wave][f0 + 1] = q2.y;
    __syncthreads();
    if (tid < 128) {
        float ss = rs[0][tid] + rs[1][tid] + rs[2][tid] + rs[3][tid];
        float qq = rq[0][tid] + rq[1][tid] + rq[2][tid] + rq[3][tid];
        float* st = stats + (size_t)(blockIdx.x & 63) * 256;
        atomicAdd(st + tid, ss);
        atomicAdd(st + 128 + tid, qq);
    }
}

// ---------------- K3: finalize BN -> per-feature scale/shift ----------------------------
__global__ void k3_finalize(const float* __restrict__ stats,
                            const float* __restrict__ gamma, const float* __restrict__ beta,
                            float* __restrict__ ssb)
{
    int f = threadIdx.x;
    if (f >= H) return;
    float s = 0.f, q = 0.f;
    for (int b = 0; b < 64; ++b) {
        s += stats[b * 256 + f];
        q += stats[b * 256 + 128 + f];
    }
    const float invE = 1.f / (float)N_EDGES;
    float mean = s * invE;
    float var = q * invE - mean * mean;
    float scale = gamma[f] * rsqrtf(var + BN_EPS);
    ssb[f] = scale;
    ssb[H + f] = beta[f] - mean * scale;
}

// ---------------- K4 (fallback): CSR pass 2 with raw ea gather --------------------------
__global__ __launch_bounds__(256) void k4_csr(
    const unsigned short* __restrict__ Ps, const unsigned short* __restrict__ Pr,
    const int* __restrict__ perm, const int* __restrict__ is_csr,
    const float* __restrict__ ea, const float* __restrict__ W1,
    const int* __restrict__ off, const int* __restrict__ deg,
    const float* __restrict__ ssb, const float* __restrict__ Winf,
    const float* __restrict__ binf_p, float* __restrict__ out)
{
    const int tid = threadIdx.x;
    const int wave = tid >> 6;
    const int lane = tid & 63;
    const int f0 = lane * 2;
    const float* Wc = W1 + 2 * H * H;

    f32x2 wc2[NUM_INV];
    #pragma unroll
    for (int k = 0; k < NUM_INV; ++k)
        wc2[k] = (f32x2){Wc[k * H + f0], Wc[k * H + f0 + 1]};

    int n = blockIdx.x * 4 + wave;
    int nu = __builtin_amdgcn_readfirstlane(n);
    int start = off[nu];
    int d = deg[nu];

    unsigned ub = *(const unsigned*)(Pr + (size_t)nu * H + f0);
    f32x2 pr2 = b2f2(ub);

    f32x2 sc2 = (f32x2){ssb[f0], ssb[f0 + 1]};
    f32x2 sh2 = (f32x2){ssb[H + f0], ssb[H + f0 + 1]};
    f32x2 wi2 = (f32x2){Winf[f0], Winf[f0 + 1]};
    float bi = binf_p[0];

    f32x2 a2 = {0.f, 0.f};
    int i = 0;
    for (; i + 2 <= d; i += 2) {
        int e0 = __builtin_amdgcn_readfirstlane(perm[start + i]);
        int e1 = __builtin_amdgcn_readfirstlane(perm[start + i + 1]);
        int is0 = __builtin_amdgcn_readfirstlane(is_csr[start + i]);
        int is1 = __builtin_amdgcn_readfirstlane(is_csr[start + i + 1]);
        unsigned ua0 = *(const unsigned*)(Ps + (size_t)is0 * H + f0);
        unsigned ua1 = *(const unsigned*)(Ps + (size_t)is1 * H + f0);
        f32x2 h0 = ea_mac(ea, e0, wc2, pr2 + b2f2(ua0));
        f32x2 h1 = ea_mac(ea, e1, wc2, pr2 + b2f2(ua1));
        h0 = h0 * sc2 + sh2;
        h1 = h1 * sc2 + sh2;
        float A0 = 1.f + __expf(-h0.x), B0 = 1.f + __expf(-h0.y);
        float A1 = 1.f + __expf(-h1.x), B1 = 1.f + __expf(-h1.y);
        float r0 = __builtin_amdgcn_rcpf(A0 * B0);
        float r1 = __builtin_amdgcn_rcpf(A1 * B1);
        f32x2 m0 = (f32x2){h0.x * B0 * r0, h0.y * A0 * r0};
        f32x2 m1 = (f32x2){h1.x * B1 * r1, h1.y * A1 * r1};
        f32x2 pp0 = m0 * wi2;
        f32x2 pp1 = m1 * wi2;
        float pt0 = wave_sum_bcast(pp0.x + pp0.y);
        float pt1 = wave_sum_bcast(pp1.x + pp1.y);
        float ew0 = __builtin_amdgcn_rcpf(1.f + __expf(-(pt0 + bi)));
        float ew1 = __builtin_amdgcn_rcpf(1.f + __expf(-(pt1 + bi)));
        a2 += m0 * splat2(ew0) + m1 * splat2(ew1);
    }
    if (i < d) {
        int e0 = __builtin_amdgcn_readfirstlane(perm[start + i]);
        int is0 = __builtin_amdgcn_readfirstlane(is_csr[start + i]);
        unsigned ua0 = *(const unsigned*)(Ps + (size_t)is0 * H + f0);
        f32x2 h0 = ea_mac(ea, e0, wc2, pr2 + b2f2(ua0));
        h0 = h0 * sc2 + sh2;
        float A0 = 1.f + __expf(-h0.x), B0 = 1.f + __expf(-h0.y);
        float r0 = __builtin_amdgcn_rcpf(A0 * B0);
        f32x2 m0 = (f32x2){h0.x * B0 * r0, h0.y * A0 * r0};
        f32x2 pp0 = m0 * wi2;
        float pt0 = wave_sum_bcast(pp0.x + pp0.y);
        float ew0 = __builtin_amdgcn_rcpf(1.f + __expf(-(pt0 + bi)));
        a2 += m0 * splat2(ew0);
    }
    *(float2*)(out + (size_t)nu * H + f0) = make_float2(a2.x, a2.y);
}

// ---------------- K4B: CSR pass 2 with streaming f16 ea + pk_fma ------------------------
__global__ __launch_bounds__(256) void k4_csrB(
    const unsigned short* __restrict__ Ps, const unsigned short* __restrict__ Pr,
    const int* __restrict__ is_csr, const unsigned short* __restrict__ eaf,
    const float* __restrict__ W1,
    const int* __restrict__ off, const int* __restrict__ deg,
    const float* __restrict__ ssb, const float* __restrict__ Winf,
    const float* __restrict__ binf_p, float* __restrict__ out)
{
    const int tid = threadIdx.x;
    const int wave = tid >> 6;
    const int lane = tid & 63;
    const int f0 = lane * 2;
    const float* Wc = W1 + 2 * H * H;

    unsigned wc16[NUM_INV];
    #pragma unroll
    for (int k = 0; k < NUM_INV; ++k)
        wc16[k] = packf16(Wc[k * H + f0], Wc[k * H + f0 + 1]);

    int n = blockIdx.x * 4 + wave;
    int nu = __builtin_amdgcn_readfirstlane(n);
    int start = off[nu];
    int d = deg[nu];

    f32x2 pr2 = b2f2(*(const unsigned*)(Pr + (size_t)nu * H + f0));
    f32x2 sc2 = (f32x2){ssb[f0], ssb[f0 + 1]};
    f32x2 sh2 = (f32x2){ssb[H + f0], ssb[H + f0 + 1]};
    f32x2 wi2 = (f32x2){Winf[f0], Winf[f0 + 1]};
    float bi = binf_p[0];

    f32x2 a2 = {0.f, 0.f};
    int i = 0;
    for (; i + 2 <= d; i += 2) {
        int is0 = __builtin_amdgcn_readfirstlane(is_csr[start + i]);
        int is1 = __builtin_amdgcn_readfirstlane(is_csr[start + i + 1]);
        unsigned ua0 = *(const unsigned*)(Ps + (size_t)is0 * H + f0);
        unsigned ua1 = *(const unsigned*)(Ps + (size_t)is1 * H + f0);
        f32x2 h0 = ea_mac_f16(eaf, start + i, wc16, pr2 + b2f2(ua0));
        f32x2 h1 = ea_mac_f16(eaf, start + i + 1, wc16, pr2 + b2f2(ua1));
        h0 = h0 * sc2 + sh2;
        h1 = h1 * sc2 + sh2;
        float A0 = 1.f + __expf(-h0.x), B0 = 1.f + __expf(-h0.y);
        float A1 = 1.f + __expf(-h1.x), B1 = 1.f + __expf(-h1.y);
        float r0 = __builtin_amdgcn_rcpf(A0 * B0);
        float r1 = __builtin_amdgcn_rcpf(A1 * B1);
        f32x2 m0 = (f32x2){h0.x * B0 * r0, h0.y * A0 * r0};
        f32x2 m1 = (f32x2){h1.x * B1 * r1, h1.y * A1 * r1};
        f32x2 pp0 = m0 * wi2;
        f32x2 pp1 = m1 * wi2;
        float pt0 = wave_sum_bcast(pp0.x + pp0.y);
        float pt1 = wave_sum_bcast(pp1.x + pp1.y);
        float ew0 = __builtin_amdgcn_rcpf(1.f + __expf(-(pt0 + bi)));
        float ew1 = __builtin_amdgcn_rcpf(1.f + __expf(-(pt1 + bi)));
        a2 += m0 * splat2(ew0) + m1 * splat2(ew1);
    }
    if (i < d) {
        int is0 = __builtin_amdgcn_readfirstlane(is_csr[start + i]);
        unsigned ua0 = *(const unsigned*)(Ps + (size_t)is0 * H + f0);
        f32x2 h0 = ea_mac_f16(eaf, start + i, wc16, pr2 + b2f2(ua0));
        h0 = h0 * sc2 + sh2;
        float A0 = 1.f + __expf(-h0.x), B0 = 1.f + __expf(-h0.y);
        float r0 = __builtin_amdgcn_rcpf(A0 * B0);
        f32x2 m0 = (f32x2){h0.x * B0 * r0, h0.y * A0 * r0};
        f32x2 pp0 = m0 * wi2;
        float pt0 = wave_sum_bcast(pp0.x + pp0.y);
        float ew0 = __builtin_amdgcn_rcpf(1.f + __expf(-(pt0 + bi)));
        a2 += m0 * splat2(ew0);
    }
    *(float2*)(out + (size_t)nu * H + f0) = make_float2(a2.x, a2.y);
}

// ---------------- launcher --------------------------------------------------------------
extern "C" void kernel_launch(void* const* d_in, const int* in_sizes, int n_in,
                              void* d_out, int out_size, void* d_ws, size_t ws_size,
                              hipStream_t stream)
{
    const float* x_send = (const float*)d_in[0];
    const float* x_rec  = (const float*)d_in[1];
    const int*   isend  = (const int*)d_in[2];
    const int*   irec   = (const int*)d_in[3];
    const float* ea     = (const float*)d_in[4];
    const float* W1     = (const float*)d_in[5];
    const float* b1     = (const float*)d_in[6];
    const float* gamma  = (const float*)d_in[7];
    const float* beta   = (const float*)d_in[8];
    const float* Winf   = (const float*)d_in[9];
    const float* binf   = (const float*)d_in[10];
    float* out = (float*)d_out;

    char* ws = (char*)d_ws;
    // shared base layout (identical to verified fallback)
    unsigned short* Ps = (unsigned short*)(ws);                     // 25,600,000
    unsigned short* Pr = (unsigned short*)(ws + 25600000);          // 25,600,000
    unsigned short* Wt = (unsigned short*)(ws + 51200000);          // 65,536
    float* stats       = (float*)(ws + 51265536);                   // 65,536
    float* ssb         = (float*)(ws + 51331072);                   // 1,024
    int* deg           = (int*)(ws + 51332096);                     // 400,000
    int* off           = (int*)(ws + 51732096);                     // 400,000
    int* cursor        = (int*)(ws + 52132096);                     // 400,000
    int* bsum          = (int*)(ws + 52532096);                     // 1,024
    int* bbase         = (int*)(ws + 52533120);                     // 1,024
    int* perm          = (int*)(ws + 52534144);                     // 6,400,000
    int* is_csr        = (int*)(ws + 58934144);                     // 6,400,000 -> 65,334,144
    unsigned short* eaf = (unsigned short*)(ws + 65334272);         // 51,200,000 -> 116,534,272

    const size_t WS_EAF_NEED = 116534272ULL;
    const int use_eaf = (ws_size >= WS_EAF_NEED) ? 1 : 0;

    hipMemsetAsync(stats, 0, 64 * 256 * sizeof(float), stream);
    hipMemsetAsync(deg, 0, N_NODES * sizeof(int), stream);

    k0_wt<<<(2 * H * H + 255) / 256, 256, 0, stream>>>(W1, Wt);
    dim3 g1(3125, 2, 1);
    k1_gemm<<<g1, 256, 0, stream>>>(x_send, x_rec, Wt, b1, Ps, Pr);

    k_deg<<<N_EDGES / 256, 256, 0, stream>>>(irec, deg);
    k_scanA<<<196, 512, 0, stream>>>(deg, bsum);
    k_scanB<<<1, 256, 0, stream>>>(bsum, bbase);
    k_scanC<<<196, 512, 0, stream>>>(deg, bbase, off, cursor);

    if (use_eaf) {
        // fused: CSR slot assignment + direct f16 ea write (sequential ea read, no perm[])
        k_permB<<<N_EDGES / 256, 256, 0, stream>>>(irec, isend, cursor, ea, is_csr, eaf);
        k2_csr<0><<<N_NODES / 4, 256, 0, stream>>>(Ps, Pr, is_csr, perm, ea, eaf, W1,
                                                   off, deg, stats);
        k3_finalize<<<1, 128, 0, stream>>>(stats, gamma, beta, ssb);
        k4_csrB<<<N_NODES / 4, 256, 0, stream>>>(Ps, Pr, is_csr, eaf, W1, off, deg,
                                                 ssb, Winf, binf, out);
    } else {
        k_perm<<<N_EDGES / 256, 256, 0, stream>>>(irec, isend, cursor, perm, is_csr);
        k2_csr<2><<<N_NODES / 4, 256, 0, stream>>>(Ps, Pr, is_csr, perm, ea, (const unsigned short*)0,
                                                   W1, off, deg, stats);
        k3_finalize<<<1, 128, 0, stream>>>(stats, gamma, beta, ssb);
        k4_csr<<<N_NODES / 4, 256, 0, stream>>>(Ps, Pr, perm, is_csr, ea, W1, off, deg,
                                                ssb, Winf, binf, out);
    }
}